// Round 3
// baseline (456.094 us; speedup 1.0000x reference)
//
#include <hip/hip_runtime.h>

#define KDIM 1024
#define NOUT 15
#define NEXP 10
#define BM   64
#define NKS  32            // KDIM / 32
#define QPT  20            // 1KB DMA units per k-slab: (n-tile 0..9) x (kt 0..1)
#define SCOL 305           // epilogue scratch stride (fp32)
#define XSTR 36            // x slab row stride in shorts (72B) -- bank-spread pad

typedef short bf16x8 __attribute__((ext_vector_type(8)));
typedef float f32x16 __attribute__((ext_vector_type(16)));

// round-to-nearest-even fp32 -> bf16 pair packed into one dword
__device__ __forceinline__ unsigned f2bf2(float a, float b) {
    unsigned ua = __float_as_uint(a);
    unsigned ub = __float_as_uint(b);
    ua = (ua + 0x7FFFu + ((ua >> 16) & 1u)) >> 16;
    ub = (ub + 0x7FFFu + ((ub >> 16) & 1u)) & 0xFFFF0000u;
    return ua | ub;
}

__device__ __forceinline__ void dma16(const void* g, void* l) {
    __builtin_amdgcn_global_load_lds(
        (const __attribute__((address_space(1))) unsigned int*)g,
        (__attribute__((address_space(3))) unsigned int*)l, 16, 0, 0);
}

// ---- pre-pass: W (expert+gate) fp32 -> bf16 workspace in exact B-fragment order ----
// unit U (16B, 8 bf16): L = U&63, q = (U>>6)%QPT, ks = U/(QPT*64)
//   nt = q>>1 (global n-tile), kt = q&1
//   B-frag lane L holds W[row = nt*32 + (L&31)][k = ks*32 + kt*16 + (L>>5)*8 + 0..7]
__global__ void wconv_kernel(const float* __restrict__ ew,
                             const float* __restrict__ gw,
                             unsigned short* __restrict__ ws)
{
    int U  = blockIdx.x * 256 + threadIdx.x;    // 0 .. 40959
    int L  = U & 63;
    int q  = (U >> 6) % QPT;
    int ks = U / (QPT * 64);
    int nt = q >> 1, kt = q & 1;
    int wrow = nt * 32 + (L & 31);
    int wcol = ks * 32 + kt * 16 + (L >> 5) * 8;
    float4 a = {0.f,0.f,0.f,0.f}, b = {0.f,0.f,0.f,0.f};
    if (wrow < 150) {
        a = *(const float4*)(ew + wrow * KDIM + wcol);
        b = *(const float4*)(ew + wrow * KDIM + wcol + 4);
    } else if (wrow < 300) {
        a = *(const float4*)(gw + (wrow - 150) * KDIM + wcol);
        b = *(const float4*)(gw + (wrow - 150) * KDIM + wcol + 4);
    }
    uint4 o;
    o.x = f2bf2(a.x, a.y); o.y = f2bf2(a.z, a.w);
    o.z = f2bf2(b.x, b.y); o.w = f2bf2(b.z, b.w);
    *(uint4*)(ws + (size_t)U * 8) = o;
}

__global__ void __launch_bounds__(256, 3)
moe_kernel(const float* __restrict__ x,
           const unsigned short* __restrict__ wsrc,
           const float* __restrict__ eb,
           const float* __restrict__ gb,
           float* __restrict__ out)
{
    __shared__ union {
        struct {
            unsigned short wb[2][QPT * 512];   // 40960 B: W double-buffered slabs (DMA dest, linear)
            unsigned short xb[2][64 * XSTR];   // 9216 B: x bf16 slabs, 72B row stride (reg-staged)
        } k;
        float ep[32][SCOL];                    // 39040 B epilogue scratch (after K loop)
    } sm;                                      // 50176 B -> 3 blocks/CU

    const int tid = threadIdx.x;
    const int wv  = tid >> 6;
    const int L   = tid & 63;
    const int mw  = wv >> 1;      // 0..1 : which 32-row half
    const int nw  = wv & 1;       // 0..1 : n-tiles nw*5 .. nw*5+4 (160 cols)
    const int ln  = L & 31;       // MFMA row (A) / col (B, C/D)
    const int lh  = L >> 5;       // k-half selector within fragment

    // coalesced x staging: thread t owns row t>>2, 32B chunk t&3
    // wave covers 16 rows x 128B fully-contiguous -> 16 cache-line txns/load
    const int srow = tid >> 2;
    const int schk = tid & 3;
    const float* xg = x + ((size_t)blockIdx.x * BM + srow) * KDIM + schk * 8;
    const int xwo = srow * XSTR + schk * 8;          // shorts offset in x slab

    // per-lane A-fragment offset (shorts) within an x slab: row mw*32+ln, k-off lh*8
    const int xfo = (mw * 32 + ln) * XSTR + lh * 8;

    f32x16 acc[5];
    #pragma unroll
    for (int nt = 0; nt < 5; ++nt)
        #pragma unroll
        for (int r = 0; r < 16; ++r)
            acc[nt][r] = 0.f;

    // ---- prologue: DMA W slab 0, stage x slab 0 to LDS, x slab 1 to regs ----
    #pragma unroll
    for (int i = 0; i < 5; ++i) {
        int q = wv * 5 + i;
        dma16(wsrc + ((size_t)q * 64 + L) * 8, &sm.k.wb[0][q * 512]);
    }
    {
        float4 a = *(const float4*)(xg);
        float4 b = *(const float4*)(xg + 4);
        uint4 o;
        o.x = f2bf2(a.x, a.y); o.y = f2bf2(a.z, a.w);
        o.z = f2bf2(b.x, b.y); o.w = f2bf2(b.z, b.w);
        *(uint4*)&sm.k.xb[0][xwo] = o;
    }
    float4 xa0 = *(const float4*)(xg + 32);
    float4 xa1 = *(const float4*)(xg + 32 + 4);
    __syncthreads();

    // ---- K loop: 32 slabs; W DMA double-buffered, x 2-deep reg prefetch + LDS dbuf ----
    #pragma unroll 2
    for (int ks = 0; ks < NKS; ++ks) {
        float4 xn0 = {0.f,0.f,0.f,0.f}, xn1 = {0.f,0.f,0.f,0.f};
        if (ks + 2 < NKS) {
            xn0 = *(const float4*)(xg + (ks + 2) * 32);
            xn1 = *(const float4*)(xg + (ks + 2) * 32 + 4);
        }
        if (ks + 1 < NKS) {
            #pragma unroll
            for (int i = 0; i < 5; ++i) {
                int q = wv * 5 + i;
                dma16(wsrc + (((size_t)(ks + 1) * QPT + q) * 64 + L) * 8,
                      &sm.k.wb[(ks + 1) & 1][q * 512]);
            }
            // convert + store next x slab (data loaded last iter, already complete)
            uint4 o;
            o.x = f2bf2(xa0.x, xa0.y); o.y = f2bf2(xa0.z, xa0.w);
            o.z = f2bf2(xa1.x, xa1.y); o.w = f2bf2(xa1.z, xa1.w);
            *(uint4*)&sm.k.xb[(ks + 1) & 1][xwo] = o;
        }

        // A fragments: one ds_read_b128 per kt, bank-spread by XSTR pad
        const unsigned short* xbuf = sm.k.xb[ks & 1];
        bf16x8 af0 = *(const bf16x8*)&xbuf[xfo];
        bf16x8 af1 = *(const bf16x8*)&xbuf[xfo + 16];

        const unsigned short* wbuf = sm.k.wb[ks & 1];
        #pragma unroll
        for (int nt = 0; nt < 5; ++nt) {
            int q = (nw * 5 + nt) * 2;
            bf16x8 b0 = *(const bf16x8*)&wbuf[q * 512 + L * 8];
            bf16x8 b1 = *(const bf16x8*)&wbuf[(q + 1) * 512 + L * 8];
            acc[nt] = __builtin_amdgcn_mfma_f32_32x32x16_bf16(af0, b0, acc[nt], 0, 0, 0);
            acc[nt] = __builtin_amdgcn_mfma_f32_32x32x16_bf16(af1, b1, acc[nt], 0, 0, 0);
        }
        __syncthreads();

        xa0 = xn0;
        xa1 = xn1;
    }

    // ---- epilogue: two 32-row phases through LDS scratch ----
    #pragma unroll 1
    for (int g = 0; g < 2; ++g) {
        if (mw == g) {
            // 32x32 C/D layout: col = lane&31, row = (reg&3) + 8*(reg>>2) + 4*(lane>>5)
            #pragma unroll
            for (int nt = 0; nt < 5; ++nt) {
                int col = nw * 160 + nt * 32 + ln;
                if (col < 300) {
                    #pragma unroll
                    for (int r = 0; r < 16; ++r)
                        sm.ep[(r & 3) + 8 * (r >> 2) + 4 * lh][col] = acc[nt][r];
                }
            }
        }
        __syncthreads();

        #pragma unroll 1
        for (int t = tid; t < 32 * NOUT; t += 256) {
            int row = t / NOUT, o = t % NOUT;
            float xi[NEXP], miu_v[NEXP];
            float mx = -1e30f;
            #pragma unroll
            for (int e = 0; e < NEXP; ++e) {
                miu_v[e] = sm.ep[row][e * NOUT + o]       + eb[e * NOUT + o];
                xi[e]    = sm.ep[row][150 + e * NOUT + o] + gb[e * NOUT + o];
                mx = fmaxf(mx, xi[e]);
            }
            float s = 0.f, v = 0.f;
            #pragma unroll
            for (int e = 0; e < NEXP; ++e) {
                float g2 = __expf(xi[e] - mx);
                s += g2;
                v += g2 * miu_v[e];
            }
            out[((size_t)blockIdx.x * BM + g * 32 + row) * NOUT + o] = v / s;
        }
        __syncthreads();
    }
}

extern "C" void kernel_launch(void* const* d_in, const int* in_sizes, int n_in,
                              void* d_out, int out_size, void* d_ws, size_t ws_size,
                              hipStream_t stream) {
    const float* x  = (const float*)d_in[0];
    const float* ew = (const float*)d_in[1];
    const float* eb = (const float*)d_in[2];
    const float* gw = (const float*)d_in[3];
    const float* gb = (const float*)d_in[4];
    float* out = (float*)d_out;
    unsigned short* ws = (unsigned short*)d_ws;   // NKS*QPT*64*16B = 640 KB

    wconv_kernel<<<160, 256, 0, stream>>>(ew, gw, ws);
    moe_kernel<<<65536 / BM, 256, 0, stream>>>(x, ws, eb, gb, out);
}

// Round 4
// 451.646 us; speedup vs baseline: 1.0098x; 1.0098x over previous
//
#include <hip/hip_runtime.h>

#define KDIM 1024
#define NOUT 15
#define NEXP 10
#define BM   128
#define NKS  32            // KDIM / 32
#define QPT  20            // 1KB DMA units per k-slab: (n-tile 0..9) x (kt 0..1)
#define SCOL 305           // epilogue scratch stride (fp32)

typedef short bf16x8 __attribute__((ext_vector_type(8)));
typedef float f32x16 __attribute__((ext_vector_type(16)));

// round-to-nearest-even fp32 -> bf16 pair packed into one dword
__device__ __forceinline__ unsigned f2bf2(float a, float b) {
    unsigned ua = __float_as_uint(a);
    unsigned ub = __float_as_uint(b);
    ua = (ua + 0x7FFFu + ((ua >> 16) & 1u)) >> 16;
    ub = (ub + 0x7FFFu + ((ub >> 16) & 1u)) & 0xFFFF0000u;
    return ua | ub;
}

__device__ __forceinline__ void dma16(const void* g, void* l) {
    __builtin_amdgcn_global_load_lds(
        (const __attribute__((address_space(1))) unsigned int*)g,
        (__attribute__((address_space(3))) unsigned int*)l, 16, 0, 0);
}

// counted-vmcnt barrier: the 5 W-DMAs (issued FIRST each iter) are the oldest
// outstanding vector-mem ops -> vmcnt(8) retires them (LDS slab visible to all
// waves after s_barrier) while the 8 x HBM loads stay in flight across it.
__device__ __forceinline__ void kbarrier() {
    __builtin_amdgcn_sched_barrier(0);
    asm volatile("s_waitcnt vmcnt(8) lgkmcnt(0)" ::: "memory");
    __builtin_amdgcn_s_barrier();
    __builtin_amdgcn_sched_barrier(0);
}

// ---- pre-pass: W (expert+gate) fp32 -> bf16 workspace in exact B-fragment order ----
// unit U (16B, 8 bf16): L = U&63, q = (U>>6)%QPT, ks = U/(QPT*64)
//   nt = q>>1 (global n-tile), kt = q&1
//   B-frag lane L holds W[row = nt*32 + (L&31)][k = ks*32 + kt*16 + (L>>5)*8 + 0..7]
__global__ void wconv_kernel(const float* __restrict__ ew,
                             const float* __restrict__ gw,
                             unsigned short* __restrict__ ws)
{
    int U  = blockIdx.x * 256 + threadIdx.x;    // 0 .. 40959
    int L  = U & 63;
    int q  = (U >> 6) % QPT;
    int ks = U / (QPT * 64);
    int nt = q >> 1, kt = q & 1;
    int wrow = nt * 32 + (L & 31);
    int wcol = ks * 32 + kt * 16 + (L >> 5) * 8;
    float4 a = {0.f,0.f,0.f,0.f}, b = {0.f,0.f,0.f,0.f};
    if (wrow < 150) {
        a = *(const float4*)(ew + wrow * KDIM + wcol);
        b = *(const float4*)(ew + wrow * KDIM + wcol + 4);
    } else if (wrow < 300) {
        a = *(const float4*)(gw + (wrow - 150) * KDIM + wcol);
        b = *(const float4*)(gw + (wrow - 150) * KDIM + wcol + 4);
    }
    uint4 o;
    o.x = f2bf2(a.x, a.y); o.y = f2bf2(a.z, a.w);
    o.z = f2bf2(b.x, b.y); o.w = f2bf2(b.z, b.w);
    *(uint4*)(ws + (size_t)U * 8) = o;
}

__global__ void __launch_bounds__(256, 2)
moe_kernel(const float* __restrict__ x,
           const unsigned short* __restrict__ wsrc,
           const float* __restrict__ eb,
           const float* __restrict__ gb,
           float* __restrict__ out)
{
    __shared__ union {
        unsigned short wb[2][QPT * 512];   // 40960 B: W double-buffered slabs (DMA dest)
        float ep[32][SCOL];                // 39040 B epilogue scratch (after K loop)
    } sm;

    const int tid = threadIdx.x;
    const int wv  = tid >> 6;
    const int L   = tid & 63;
    const int mw  = wv >> 1;      // 0..1 : row-strip parity
    const int nw  = wv & 1;       // 0..1 : n-tiles nw*5 .. nw*5+4 (160 cols)
    const int ln  = L & 31;       // MFMA row (A) / col (B, C/D)
    const int lh  = L >> 5;       // k-half selector within fragment

    // each wave owns TWO 32-row strips: rows (mw+2h)*32 .. +31, h=0,1
    const float* xrow0 = x + ((size_t)blockIdx.x * BM + mw * 32 + ln) * KDIM + lh * 8;
    const float* xrow1 = xrow0 + (size_t)64 * KDIM;

    f32x16 acc[2][5];
    #pragma unroll
    for (int h = 0; h < 2; ++h)
        #pragma unroll
        for (int nt = 0; nt < 5; ++nt)
            #pragma unroll
            for (int r = 0; r < 16; ++r)
                acc[h][nt][r] = 0.f;

    // ---- prologue: DMA W slab 0 (first!), then load x slab 0 ----
    #pragma unroll
    for (int i = 0; i < 5; ++i) {
        int q = wv * 5 + i;
        dma16(wsrc + ((size_t)q * 64 + L) * 8, &sm.wb[0][q * 512]);
    }
    __builtin_amdgcn_sched_barrier(0);
    float4 xa[2][2][2];
    #pragma unroll
    for (int kt = 0; kt < 2; ++kt) {
        xa[0][kt][0] = *(const float4*)(xrow0 + kt * 16);
        xa[0][kt][1] = *(const float4*)(xrow0 + kt * 16 + 4);
        xa[1][kt][0] = *(const float4*)(xrow1 + kt * 16);
        xa[1][kt][1] = *(const float4*)(xrow1 + kt * 16 + 4);
    }
    kbarrier();

    // ---- K loop: 32 slabs; W DMA double-buffered; counted-vmcnt barrier ----
    #pragma unroll 2
    for (int ks = 0; ks < NKS; ++ks) {
        // 1) W DMAs for next slab -- issued FIRST (oldest in vmcnt queue)
        if (ks + 1 < NKS) {
            #pragma unroll
            for (int i = 0; i < 5; ++i) {
                int q = wv * 5 + i;
                dma16(wsrc + (((size_t)(ks + 1) * QPT + q) * 64 + L) * 8,
                      &sm.wb[(ks + 1) & 1][q * 512]);
            }
        }
        __builtin_amdgcn_sched_barrier(0);

        // 2) pack current x slab (loaded last iter; waits only its own loads)
        bf16x8 af[2][2];
        #pragma unroll
        for (int h = 0; h < 2; ++h)
            #pragma unroll
            for (int kt = 0; kt < 2; ++kt) {
                union { unsigned u[4]; bf16x8 v; } pk;
                pk.u[0] = f2bf2(xa[h][kt][0].x, xa[h][kt][0].y);
                pk.u[1] = f2bf2(xa[h][kt][0].z, xa[h][kt][0].w);
                pk.u[2] = f2bf2(xa[h][kt][1].x, xa[h][kt][1].y);
                pk.u[3] = f2bf2(xa[h][kt][1].z, xa[h][kt][1].w);
                af[h][kt] = pk.v;
            }

        // 3) x loads for next slab (stay in flight across the barrier)
        if (ks + 1 < NKS) {
            #pragma unroll
            for (int kt = 0; kt < 2; ++kt) {
                xa[0][kt][0] = *(const float4*)(xrow0 + (ks + 1) * 32 + kt * 16);
                xa[0][kt][1] = *(const float4*)(xrow0 + (ks + 1) * 32 + kt * 16 + 4);
                xa[1][kt][0] = *(const float4*)(xrow1 + (ks + 1) * 32 + kt * 16);
                xa[1][kt][1] = *(const float4*)(xrow1 + (ks + 1) * 32 + kt * 16 + 4);
            }
        }

        // 4) MFMA: B frags shared across both row-strips
        const unsigned short* wbuf = sm.wb[ks & 1];
        #pragma unroll
        for (int nt = 0; nt < 5; ++nt) {
            int q = (nw * 5 + nt) * 2;
            bf16x8 b0 = *(const bf16x8*)&wbuf[q * 512 + L * 8];
            bf16x8 b1 = *(const bf16x8*)&wbuf[(q + 1) * 512 + L * 8];
            acc[0][nt] = __builtin_amdgcn_mfma_f32_32x32x16_bf16(af[0][0], b0, acc[0][nt], 0, 0, 0);
            acc[1][nt] = __builtin_amdgcn_mfma_f32_32x32x16_bf16(af[1][0], b0, acc[1][nt], 0, 0, 0);
            acc[0][nt] = __builtin_amdgcn_mfma_f32_32x32x16_bf16(af[0][1], b1, acc[0][nt], 0, 0, 0);
            acc[1][nt] = __builtin_amdgcn_mfma_f32_32x32x16_bf16(af[1][1], b1, acc[1][nt], 0, 0, 0);
        }

        // 5) counted barrier: W DMAs retired, x loads remain in flight
        kbarrier();
    }

    __syncthreads();   // full drain before re-using LDS union as epilogue scratch

    // ---- epilogue: four 32-row phases through LDS scratch ----
    #pragma unroll 1
    for (int g = 0; g < 4; ++g) {
        if (mw == (g & 1)) {
            int h = g >> 1;
            // 32x32 C/D layout: col = lane&31, row = (reg&3) + 8*(reg>>2) + 4*(lane>>5)
            #pragma unroll
            for (int nt = 0; nt < 5; ++nt) {
                int col = nw * 160 + nt * 32 + ln;
                if (col < 300) {
                    #pragma unroll
                    for (int r = 0; r < 16; ++r)
                        sm.ep[(r & 3) + 8 * (r >> 2) + 4 * lh][col] = acc[h][nt][r];
                }
            }
        }
        __syncthreads();

        #pragma unroll 1
        for (int t = tid; t < 32 * NOUT; t += 256) {
            int row = t / NOUT, o = t % NOUT;
            float xi[NEXP], miu_v[NEXP];
            float mx = -1e30f;
            #pragma unroll
            for (int e = 0; e < NEXP; ++e) {
                miu_v[e] = sm.ep[row][e * NOUT + o]       + eb[e * NOUT + o];
                xi[e]    = sm.ep[row][150 + e * NOUT + o] + gb[e * NOUT + o];
                mx = fmaxf(mx, xi[e]);
            }
            float s = 0.f, v = 0.f;
            #pragma unroll
            for (int e = 0; e < NEXP; ++e) {
                float g2 = __expf(xi[e] - mx);
                s += g2;
                v += g2 * miu_v[e];
            }
            out[((size_t)blockIdx.x * BM + g * 32 + row) * NOUT + o] = v / s;
        }
        __syncthreads();
    }
}

extern "C" void kernel_launch(void* const* d_in, const int* in_sizes, int n_in,
                              void* d_out, int out_size, void* d_ws, size_t ws_size,
                              hipStream_t stream) {
    const float* x  = (const float*)d_in[0];
    const float* ew = (const float*)d_in[1];
    const float* eb = (const float*)d_in[2];
    const float* gw = (const float*)d_in[3];
    const float* gb = (const float*)d_in[4];
    float* out = (float*)d_out;
    unsigned short* ws = (unsigned short*)d_ws;   // NKS*QPT*64*16B = 640 KB

    wconv_kernel<<<160, 256, 0, stream>>>(ew, gw, ws);
    moe_kernel<<<65536 / BM, 256, 0, stream>>>(x, ws, eb, gb, out);
}

// Round 6
// 423.287 us; speedup vs baseline: 1.0775x; 1.0670x over previous
//
#include <hip/hip_runtime.h>

#define KDIM 1024
#define NOUT 15
#define NEXP 10
#define BM   64
#define NKS  32            // KDIM / 32
#define QPT  20            // 1KB DMA units per k-slab: (n-tile 0..9) x (kt 0..1)
#define SCOL 305           // epilogue scratch stride (fp32)

typedef short bf16x8 __attribute__((ext_vector_type(8)));
typedef float f32x16 __attribute__((ext_vector_type(16)));

// round-to-nearest-even fp32 -> bf16 pair packed into one dword
__device__ __forceinline__ unsigned f2bf2(float a, float b) {
    unsigned ua = __float_as_uint(a);
    unsigned ub = __float_as_uint(b);
    ua = (ua + 0x7FFFu + ((ua >> 16) & 1u)) >> 16;
    ub = (ub + 0x7FFFu + ((ub >> 16) & 1u)) & 0xFFFF0000u;
    return ua | ub;
}

__device__ __forceinline__ void dma16(const void* g, void* l) {
    __builtin_amdgcn_global_load_lds(
        (const __attribute__((address_space(1))) unsigned int*)g,
        (__attribute__((address_space(3))) unsigned int*)l, 16, 0, 0);
}

// counted-vmcnt barrier: each wave's 5 W-DMAs (issued FIRST in the stage) are
// its oldest outstanding vmem ops -> vmcnt(8) retires exactly them (slab
// visible in LDS), while the 8 x HBM loads stay in flight across s_barrier.
__device__ __forceinline__ void kbarrier() {
    __builtin_amdgcn_sched_barrier(0);
    asm volatile("s_waitcnt vmcnt(8) lgkmcnt(0)" ::: "memory");
    __builtin_amdgcn_s_barrier();
    __builtin_amdgcn_sched_barrier(0);
}

// ---- pre-pass: W (expert+gate) fp32 -> bf16 workspace in exact B-fragment order ----
// unit U (16B, 8 bf16): L = U&63, q = (U>>6)%QPT, ks = U/(QPT*64)
//   nt = q>>1 (global n-tile), kt = q&1
//   B-frag lane L holds W[row = nt*32 + (L&31)][k = ks*32 + kt*16 + (L>>5)*8 + 0..7]
__global__ void wconv_kernel(const float* __restrict__ ew,
                             const float* __restrict__ gw,
                             unsigned short* __restrict__ ws)
{
    int U  = blockIdx.x * 256 + threadIdx.x;    // 0 .. 40959
    int L  = U & 63;
    int q  = (U >> 6) % QPT;
    int ks = U / (QPT * 64);
    int nt = q >> 1, kt = q & 1;
    int wrow = nt * 32 + (L & 31);
    int wcol = ks * 32 + kt * 16 + (L >> 5) * 8;
    float4 a = {0.f,0.f,0.f,0.f}, b = {0.f,0.f,0.f,0.f};
    if (wrow < 150) {
        a = *(const float4*)(ew + wrow * KDIM + wcol);
        b = *(const float4*)(ew + wrow * KDIM + wcol + 4);
    } else if (wrow < 300) {
        a = *(const float4*)(gw + (wrow - 150) * KDIM + wcol);
        b = *(const float4*)(gw + (wrow - 150) * KDIM + wcol + 4);
    }
    uint4 o;
    o.x = f2bf2(a.x, a.y); o.y = f2bf2(a.z, a.w);
    o.z = f2bf2(b.x, b.y); o.w = f2bf2(b.z, b.w);
    *(uint4*)(ws + (size_t)U * 8) = o;
}

__global__ void __launch_bounds__(256, 3)
moe_kernel(const float* __restrict__ x,
           const unsigned short* __restrict__ wsrc,
           const float* __restrict__ eb,
           const float* __restrict__ gb,
           float* __restrict__ out)
{
    __shared__ union {
        unsigned short wb[2][QPT * 512];   // 40960 B: W double-buffered slabs (DMA dest)
        float ep[32][SCOL];                // 39040 B epilogue scratch (after K loop)
    } sm;

    const int tid = threadIdx.x;
    const int wv  = tid >> 6;
    const int L   = tid & 63;
    const int mw  = wv >> 1;      // 0..1 : which 32-row half
    const int nw  = wv & 1;       // 0..1 : n-tiles nw*5 .. nw*5+4 (160 cols)
    const int ln  = L & 31;       // MFMA row (A) / col (B, C/D)
    const int lh  = L >> 5;       // k-half selector within fragment

    // this lane's X row pointer (frag k-offset baked in)
    const float* xrow = x + ((size_t)blockIdx.x * BM + mw * 32 + ln) * KDIM + lh * 8;

    f32x16 acc[5];
    #pragma unroll
    for (int nt = 0; nt < 5; ++nt)
        #pragma unroll
        for (int r = 0; r < 16; ++r)
            acc[nt][r] = 0.f;

    float4 xa[2][2], xb[2][2];

    // ---- prologue: DMA W slab 0 FIRST, then x slab 0 -> xa ----
    #pragma unroll
    for (int i = 0; i < 5; ++i) {
        int q = wv * 5 + i;
        dma16(wsrc + ((size_t)q * 64 + L) * 8, &sm.wb[0][q * 512]);
    }
    __builtin_amdgcn_sched_barrier(0);
    #pragma unroll
    for (int kt = 0; kt < 2; ++kt) {
        xa[kt][0] = *(const float4*)(xrow + kt * 16);
        xa[kt][1] = *(const float4*)(xrow + kt * 16 + 4);
    }
    kbarrier();

    // ---- K loop: two slabs per trip, named register sets (no copies) ----
    #pragma unroll 1
    for (int ks2 = 0; ks2 < NKS; ks2 += 2) {
        // ======== stage A: compute slab ks2 (xa), prefetch slab ks2+1 (xb) ========
        {
            const int kn = ks2 + 1;   // always < NKS
            #pragma unroll
            for (int i = 0; i < 5; ++i) {
                int q = wv * 5 + i;
                dma16(wsrc + (((size_t)kn * QPT + q) * 64 + L) * 8,
                      &sm.wb[kn & 1][q * 512]);
            }
            __builtin_amdgcn_sched_barrier(0);
            #pragma unroll
            for (int kt = 0; kt < 2; ++kt) {
                xb[kt][0] = *(const float4*)(xrow + kn * 32 + kt * 16);
                xb[kt][1] = *(const float4*)(xrow + kn * 32 + kt * 16 + 4);
            }
            __builtin_amdgcn_sched_barrier(0);

            bf16x8 af[2];
            #pragma unroll
            for (int kt = 0; kt < 2; ++kt) {
                union { unsigned u[4]; bf16x8 v; } pk;
                pk.u[0] = f2bf2(xa[kt][0].x, xa[kt][0].y);
                pk.u[1] = f2bf2(xa[kt][0].z, xa[kt][0].w);
                pk.u[2] = f2bf2(xa[kt][1].x, xa[kt][1].y);
                pk.u[3] = f2bf2(xa[kt][1].z, xa[kt][1].w);
                af[kt] = pk.v;
            }
            const unsigned short* wbuf = sm.wb[ks2 & 1];
            #pragma unroll
            for (int nt = 0; nt < 5; ++nt) {
                int q = (nw * 5 + nt) * 2;
                bf16x8 b0 = *(const bf16x8*)&wbuf[q * 512 + L * 8];
                bf16x8 b1 = *(const bf16x8*)&wbuf[(q + 1) * 512 + L * 8];
                acc[nt] = __builtin_amdgcn_mfma_f32_32x32x16_bf16(af[0], b0, acc[nt], 0, 0, 0);
                acc[nt] = __builtin_amdgcn_mfma_f32_32x32x16_bf16(af[1], b1, acc[nt], 0, 0, 0);
            }
            kbarrier();
        }
        // ======== stage B: compute slab ks2+1 (xb), prefetch slab ks2+2 (xa) ========
        {
            const int kn = ks2 + 2;
            if (kn < NKS) {
                #pragma unroll
                for (int i = 0; i < 5; ++i) {
                    int q = wv * 5 + i;
                    dma16(wsrc + (((size_t)kn * QPT + q) * 64 + L) * 8,
                          &sm.wb[kn & 1][q * 512]);
                }
                __builtin_amdgcn_sched_barrier(0);
                #pragma unroll
                for (int kt = 0; kt < 2; ++kt) {
                    xa[kt][0] = *(const float4*)(xrow + kn * 32 + kt * 16);
                    xa[kt][1] = *(const float4*)(xrow + kn * 32 + kt * 16 + 4);
                }
            }
            __builtin_amdgcn_sched_barrier(0);

            bf16x8 af[2];
            #pragma unroll
            for (int kt = 0; kt < 2; ++kt) {
                union { unsigned u[4]; bf16x8 v; } pk;
                pk.u[0] = f2bf2(xb[kt][0].x, xb[kt][0].y);
                pk.u[1] = f2bf2(xb[kt][0].z, xb[kt][0].w);
                pk.u[2] = f2bf2(xb[kt][1].x, xb[kt][1].y);
                pk.u[3] = f2bf2(xb[kt][1].z, xb[kt][1].w);
                af[kt] = pk.v;
            }
            const unsigned short* wbuf = sm.wb[(ks2 + 1) & 1];
            #pragma unroll
            for (int nt = 0; nt < 5; ++nt) {
                int q = (nw * 5 + nt) * 2;
                bf16x8 b0 = *(const bf16x8*)&wbuf[q * 512 + L * 8];
                bf16x8 b1 = *(const bf16x8*)&wbuf[(q + 1) * 512 + L * 8];
                acc[nt] = __builtin_amdgcn_mfma_f32_32x32x16_bf16(af[0], b0, acc[nt], 0, 0, 0);
                acc[nt] = __builtin_amdgcn_mfma_f32_32x32x16_bf16(af[1], b1, acc[nt], 0, 0, 0);
            }
            kbarrier();
        }
    }

    // ---- epilogue: two 32-row phases through LDS scratch ----
    #pragma unroll 1
    for (int g = 0; g < 2; ++g) {
        if (mw == g) {
            // 32x32 C/D layout: col = lane&31, row = (reg&3) + 8*(reg>>2) + 4*(lane>>5)
            #pragma unroll
            for (int nt = 0; nt < 5; ++nt) {
                int col = nw * 160 + nt * 32 + ln;
                if (col < 300) {
                    #pragma unroll
                    for (int r = 0; r < 16; ++r)
                        sm.ep[(r & 3) + 8 * (r >> 2) + 4 * lh][col] = acc[nt][r];
                }
            }
        }
        __syncthreads();

        #pragma unroll 1
        for (int t = tid; t < 32 * NOUT; t += 256) {
            int row = t / NOUT, o = t % NOUT;
            float xi[NEXP], miu_v[NEXP];
            float mx = -1e30f;
            #pragma unroll
            for (int e = 0; e < NEXP; ++e) {
                miu_v[e] = sm.ep[row][e * NOUT + o]       + eb[e * NOUT + o];
                xi[e]    = sm.ep[row][150 + e * NOUT + o] + gb[e * NOUT + o];
                mx = fmaxf(mx, xi[e]);
            }
            float s = 0.f, v = 0.f;
            #pragma unroll
            for (int e = 0; e < NEXP; ++e) {
                float g2 = __expf(xi[e] - mx);
                s += g2;
                v += g2 * miu_v[e];
            }
            out[((size_t)blockIdx.x * BM + g * 32 + row) * NOUT + o] = v / s;
        }
        __syncthreads();
    }
}

extern "C" void kernel_launch(void* const* d_in, const int* in_sizes, int n_in,
                              void* d_out, int out_size, void* d_ws, size_t ws_size,
                              hipStream_t stream) {
    const float* x  = (const float*)d_in[0];
    const float* ew = (const float*)d_in[1];
    const float* eb = (const float*)d_in[2];
    const float* gw = (const float*)d_in[3];
    const float* gb = (const float*)d_in[4];
    float* out = (float*)d_out;
    unsigned short* ws = (unsigned short*)d_ws;   // NKS*QPT*64*16B = 640 KB

    wconv_kernel<<<160, 256, 0, stream>>>(ew, gw, ws);
    moe_kernel<<<65536 / BM, 256, 0, stream>>>(x, ws, eb, gb, out);
}

// Round 7
// 397.701 us; speedup vs baseline: 1.1468x; 1.0643x over previous
//
#include <hip/hip_runtime.h>

#define KDIM 1024
#define NOUT 15
#define NEXP 10
#define BM   64
#define NKS  32            // KDIM / 32
#define QPT  20            // 1KB DMA units per k-slab: (n-tile 0..9) x (kt 0..1)
#define SCOL 305           // epilogue scratch stride (fp32)
#define XSTR 40            // x slab row stride in shorts (80 B, 16B-aligned rows)

typedef short bf16x8 __attribute__((ext_vector_type(8)));
typedef float f32x16 __attribute__((ext_vector_type(16)));

// round-to-nearest-even fp32 -> bf16 pair packed into one dword
__device__ __forceinline__ unsigned f2bf2(float a, float b) {
    unsigned ua = __float_as_uint(a);
    unsigned ub = __float_as_uint(b);
    ua = (ua + 0x7FFFu + ((ua >> 16) & 1u)) >> 16;
    ub = (ub + 0x7FFFu + ((ub >> 16) & 1u)) & 0xFFFF0000u;
    return ua | ub;
}

__device__ __forceinline__ void dma16(const void* g, void* l) {
    __builtin_amdgcn_global_load_lds(
        (const __attribute__((address_space(1))) unsigned int*)g,
        (__attribute__((address_space(3))) unsigned int*)l, 16, 0, 0);
}

// counted barrier: each wave's 5 W-DMAs (issued FIRST in the stage) are its
// oldest outstanding vmem ops -> vmcnt(2) retires exactly them (slab visible
// in LDS) while the 2 x staging loads stay in flight across s_barrier.
__device__ __forceinline__ void kbar2() {
    __builtin_amdgcn_sched_barrier(0);
    asm volatile("s_waitcnt vmcnt(2) lgkmcnt(0)" ::: "memory");
    __builtin_amdgcn_s_barrier();
    __builtin_amdgcn_sched_barrier(0);
}
// full-drain barrier for the peeled last trip (no x loads in flight)
__device__ __forceinline__ void kbar0() {
    __builtin_amdgcn_sched_barrier(0);
    asm volatile("s_waitcnt vmcnt(0) lgkmcnt(0)" ::: "memory");
    __builtin_amdgcn_s_barrier();
    __builtin_amdgcn_sched_barrier(0);
}

// convert 8 fp32 -> 8 bf16, one 16B LDS write (staging thread's slab share)
__device__ __forceinline__ void xwrite(unsigned short* xs, int xwo, const float4 (&v)[2]) {
    uint4 o;
    o.x = f2bf2(v[0].x, v[0].y); o.y = f2bf2(v[0].z, v[0].w);
    o.z = f2bf2(v[1].x, v[1].y); o.w = f2bf2(v[1].z, v[1].w);
    *(uint4*)&xs[xwo] = o;
}

// one k-slab of MFMA work: A frags from staged x slab, B frags from W slab
__device__ __forceinline__ void compute_slab(const unsigned short* wbuf,
                                             const unsigned short* xbuf,
                                             int xfo, int nw, int L,
                                             f32x16 (&acc)[5])
{
    bf16x8 af0 = *(const bf16x8*)&xbuf[xfo];        // kt=0
    bf16x8 af1 = *(const bf16x8*)&xbuf[xfo + 16];   // kt=1
    #pragma unroll
    for (int nt = 0; nt < 5; ++nt) {
        int q = (nw * 5 + nt) * 2;
        bf16x8 b0 = *(const bf16x8*)&wbuf[q * 512 + L * 8];
        bf16x8 b1 = *(const bf16x8*)&wbuf[(q + 1) * 512 + L * 8];
        acc[nt] = __builtin_amdgcn_mfma_f32_32x32x16_bf16(af0, b0, acc[nt], 0, 0, 0);
        acc[nt] = __builtin_amdgcn_mfma_f32_32x32x16_bf16(af1, b1, acc[nt], 0, 0, 0);
    }
}

// ---- pre-pass: W (expert+gate) fp32 -> bf16 workspace in exact B-fragment order ----
__global__ void wconv_kernel(const float* __restrict__ ew,
                             const float* __restrict__ gw,
                             unsigned short* __restrict__ ws)
{
    int U  = blockIdx.x * 256 + threadIdx.x;    // 0 .. 40959
    int L  = U & 63;
    int q  = (U >> 6) % QPT;
    int ks = U / (QPT * 64);
    int nt = q >> 1, kt = q & 1;
    int wrow = nt * 32 + (L & 31);
    int wcol = ks * 32 + kt * 16 + (L >> 5) * 8;
    float4 a = {0.f,0.f,0.f,0.f}, b = {0.f,0.f,0.f,0.f};
    if (wrow < 150) {
        a = *(const float4*)(ew + wrow * KDIM + wcol);
        b = *(const float4*)(ew + wrow * KDIM + wcol + 4);
    } else if (wrow < 300) {
        a = *(const float4*)(gw + (wrow - 150) * KDIM + wcol);
        b = *(const float4*)(gw + (wrow - 150) * KDIM + wcol + 4);
    }
    uint4 o;
    o.x = f2bf2(a.x, a.y); o.y = f2bf2(a.z, a.w);
    o.z = f2bf2(b.x, b.y); o.w = f2bf2(b.z, b.w);
    *(uint4*)(ws + (size_t)U * 8) = o;
}

__global__ void __launch_bounds__(256, 3)
moe_kernel(const float* __restrict__ x,
           const unsigned short* __restrict__ wsrc,
           const float* __restrict__ eb,
           const float* __restrict__ gb,
           float* __restrict__ out)
{
    __shared__ union {
        struct {
            unsigned short wb[2][QPT * 512];   // 40960 B: W double-buffered slabs (DMA dest)
            unsigned short xs[2][64 * XSTR];   // 10240 B: x bf16 slabs, coalesced-staged
        } k;
        float ep[32][SCOL];                    // 39040 B epilogue scratch (after K loop)
    } sm;                                      // 51200 B -> 3 blocks/CU

    const int tid = threadIdx.x;
    const int wv  = tid >> 6;
    const int L   = tid & 63;
    const int mw  = wv >> 1;      // 0..1 : which 32-row half
    const int nw  = wv & 1;       // 0..1 : n-tiles nw*5 .. nw*5+4 (160 cols)
    const int ln  = L & 31;       // MFMA row (A) / col (B, C/D)
    const int lh  = L >> 5;       // k-half selector within fragment

    // coalesced staging: thread t owns row t>>2, 32B chunk t&3
    // wave's load = 16 cache lines (vs 64 for per-lane row access)
    const float* xg = x + ((size_t)blockIdx.x * BM + (tid >> 2)) * KDIM + (tid & 3) * 8;
    const int xwo = (tid >> 2) * XSTR + (tid & 3) * 8;      // staging write offset (shorts)
    const int xfo = (mw * 32 + ln) * XSTR + lh * 8;         // A-frag read offset (shorts)

    f32x16 acc[5];
    #pragma unroll
    for (int nt = 0; nt < 5; ++nt)
        #pragma unroll
        for (int r = 0; r < 16; ++r)
            acc[nt][r] = 0.f;

    float4 xa[2], xb[2];

    // ---- prologue: DMA W0 (oldest), load+stage x slab 0, load slab 1 -> xa ----
    #pragma unroll
    for (int i = 0; i < 5; ++i) {
        int q = wv * 5 + i;
        dma16(wsrc + ((size_t)q * 64 + L) * 8, &sm.k.wb[0][q * 512]);
    }
    __builtin_amdgcn_sched_barrier(0);
    {
        float4 xt[2];
        xt[0] = *(const float4*)(xg);
        xt[1] = *(const float4*)(xg + 4);
        __builtin_amdgcn_sched_barrier(0);
        xa[0] = *(const float4*)(xg + 32);
        xa[1] = *(const float4*)(xg + 32 + 4);
        __builtin_amdgcn_sched_barrier(0);
        xwrite(sm.k.xs[0], xwo, xt);    // compiler-inserted wait drains W0+slab0 loads
    }
    kbar2();                            // xa's 2 loads stay in flight

    // ---- K loop: 2 slabs/trip; W DMA dbuf + x 2-stage reg pipeline + staged LDS ----
    #pragma unroll 1
    for (int s = 0; s < 30; s += 2) {
        // === stage A: compute slab s; xa holds s+1; prefetch s+2 -> xb ===
        #pragma unroll
        for (int i = 0; i < 5; ++i) {
            int q = wv * 5 + i;
            dma16(wsrc + (((size_t)(s + 1) * QPT + q) * 64 + L) * 8,
                  &sm.k.wb[(s + 1) & 1][q * 512]);
        }
        __builtin_amdgcn_sched_barrier(0);
        xb[0] = *(const float4*)(xg + (s + 2) * 32);
        xb[1] = *(const float4*)(xg + (s + 2) * 32 + 4);
        __builtin_amdgcn_sched_barrier(0);
        xwrite(sm.k.xs[(s + 1) & 1], xwo, xa);   // waits only xa (vmcnt(7))
        compute_slab(sm.k.wb[s & 1], sm.k.xs[s & 1], xfo, nw, L, acc);
        kbar2();

        // === stage B: compute slab s+1; xb holds s+2; prefetch s+3 -> xa ===
        #pragma unroll
        for (int i = 0; i < 5; ++i) {
            int q = wv * 5 + i;
            dma16(wsrc + (((size_t)(s + 2) * QPT + q) * 64 + L) * 8,
                  &sm.k.wb[s & 1][q * 512]);
        }
        __builtin_amdgcn_sched_barrier(0);
        xa[0] = *(const float4*)(xg + (s + 3) * 32);
        xa[1] = *(const float4*)(xg + (s + 3) * 32 + 4);
        __builtin_amdgcn_sched_barrier(0);
        xwrite(sm.k.xs[s & 1], xwo, xb);
        compute_slab(sm.k.wb[(s + 1) & 1], sm.k.xs[(s + 1) & 1], xfo, nw, L, acc);
        kbar2();
    }

    // ---- peeled last trip: slabs 30, 31 (no x loads in flight -> vmcnt(0)) ----
    {
        #pragma unroll
        for (int i = 0; i < 5; ++i) {
            int q = wv * 5 + i;
            dma16(wsrc + (((size_t)31 * QPT + q) * 64 + L) * 8, &sm.k.wb[1][q * 512]);
        }
        __builtin_amdgcn_sched_barrier(0);
        xwrite(sm.k.xs[1], xwo, xa);    // slab 31 (loaded in last loop stage B)
        compute_slab(sm.k.wb[0], sm.k.xs[0], xfo, nw, L, acc);   // slab 30
        kbar0();
        compute_slab(sm.k.wb[1], sm.k.xs[1], xfo, nw, L, acc);   // slab 31
        __syncthreads();
    }

    // ---- epilogue: two 32-row phases through LDS scratch ----
    #pragma unroll 1
    for (int g = 0; g < 2; ++g) {
        if (mw == g) {
            // 32x32 C/D layout: col = lane&31, row = (reg&3) + 8*(reg>>2) + 4*(lane>>5)
            #pragma unroll
            for (int nt = 0; nt < 5; ++nt) {
                int col = nw * 160 + nt * 32 + ln;
                if (col < 300) {
                    #pragma unroll
                    for (int r = 0; r < 16; ++r)
                        sm.ep[(r & 3) + 8 * (r >> 2) + 4 * lh][col] = acc[nt][r];
                }
            }
        }
        __syncthreads();

        #pragma unroll 1
        for (int t = tid; t < 32 * NOUT; t += 256) {
            int row = t / NOUT, o = t % NOUT;
            float xi[NEXP], miu_v[NEXP];
            float mx = -1e30f;
            #pragma unroll
            for (int e = 0; e < NEXP; ++e) {
                miu_v[e] = sm.ep[row][e * NOUT + o]       + eb[e * NOUT + o];
                xi[e]    = sm.ep[row][150 + e * NOUT + o] + gb[e * NOUT + o];
                mx = fmaxf(mx, xi[e]);
            }
            float s = 0.f, v = 0.f;
            #pragma unroll
            for (int e = 0; e < NEXP; ++e) {
                float g2 = __expf(xi[e] - mx);
                s += g2;
                v += g2 * miu_v[e];
            }
            out[((size_t)blockIdx.x * BM + g * 32 + row) * NOUT + o] = v / s;
        }
        __syncthreads();
    }
}

extern "C" void kernel_launch(void* const* d_in, const int* in_sizes, int n_in,
                              void* d_out, int out_size, void* d_ws, size_t ws_size,
                              hipStream_t stream) {
    const float* x  = (const float*)d_in[0];
    const float* ew = (const float*)d_in[1];
    const float* eb = (const float*)d_in[2];
    const float* gw = (const float*)d_in[3];
    const float* gb = (const float*)d_in[4];
    float* out = (float*)d_out;
    unsigned short* ws = (unsigned short*)d_ws;   // NKS*QPT*64*16B = 640 KB

    wconv_kernel<<<160, 256, 0, stream>>>(ew, gw, ws);
    moe_kernel<<<65536 / BM, 256, 0, stream>>>(x, ws, eb, gb, out);
}